// Round 5
// baseline (340.208 us; speedup 1.0000x reference)
//
#include <hip/hip_runtime.h>
#include <hip/hip_bf16.h>

constexpr int B_ = 4;
constexpr int T_ = 2048;
constexpr int DIM_ = 1024;
constexpr int H_ = 8;
constexpr int D_ = 128;
constexpr int HDIM_ = H_ * D_;   // 1024

typedef __attribute__((ext_vector_type(8))) short bf16x8;
typedef __attribute__((ext_vector_type(8))) unsigned short ushort8;
typedef __attribute__((ext_vector_type(4))) float f32x4;

#define ATTN_SCALE 0.08838834764831845f

__device__ __forceinline__ unsigned short f2bf(float x) {
    unsigned u = __float_as_uint(x);
    unsigned r = (u + 0x7FFFu + ((u >> 16) & 1u)) >> 16;
    return (unsigned short)r;
}
__device__ __forceinline__ float bf2f(unsigned short u) {
    return __uint_as_float(((unsigned)u) << 16);
}

// async 16B global -> LDS (dest: wave-uniform base + lane*16; src: per-lane)
__device__ __forceinline__ void async_ld16(void* ldsdst, const void* gsrc) {
    __builtin_amdgcn_global_load_lds(
        (const __attribute__((address_space(1))) unsigned int*)gsrc,
        (__attribute__((address_space(3))) unsigned int*)ldsdst, 16, 0, 0);
}

// ---------------------------------------------------------------------------
// f32 -> bf16 convert, 4 elems/thread
// ---------------------------------------------------------------------------
__global__ __launch_bounds__(256) void cvtk(const float* __restrict__ in,
                                            unsigned short* __restrict__ out, int n4) {
    int i = blockIdx.x * 256 + threadIdx.x;
    if (i < n4) {
        float4 v = ((const float4*)in)[i];
        ushort4 o;
        o.x = f2bf(v.x); o.y = f2bf(v.y); o.z = f2bf(v.z); o.w = f2bf(v.w);
        ((ushort4*)out)[i] = o;
    }
}

// ---------------------------------------------------------------------------
// RoPE tables (f32): cos/sin[t][j], j<32 real freqs; j>=32 identity.
// ---------------------------------------------------------------------------
__global__ void rope_tables_k(float* __restrict__ cost, float* __restrict__ sint) {
    int idx = blockIdx.x * blockDim.x + threadIdx.x;
    if (idx >= T_ * 32) return;
    int t = idx >> 5, j = idx & 31;
    float e = (float)j * (1.0f / 31.0f);
    float freq = powf(1.0f / 1024.0f, e);
    float th = (float)t * freq;
    cost[idx] = cosf(th);
    sint[idx] = sinf(th);
}

// ---------------------------------------------------------------------------
// bf16 NT GEMM: C[M,N] = A[M,K] * B[N,K]^T, 128x128 tile, BK=64, 4 waves 2x2.
// (unchanged from round 4 — verified)
// ---------------------------------------------------------------------------
__global__ __launch_bounds__(256) void gemm_bf16_nt(
    const unsigned short* __restrict__ A, const unsigned short* __restrict__ Bw,
    float* __restrict__ Cf, unsigned short* __restrict__ Cb,
    int M, int N, int K) {
    __shared__ __align__(16) unsigned short As[128 * 64];
    __shared__ __align__(16) unsigned short Bs[128 * 64];
    const int tid = threadIdx.x;
    const int l = tid & 63, w = tid >> 6;
    const int g = l >> 4, q16 = l & 15;

    int nwg = gridDim.x * gridDim.y;
    int lin = blockIdx.y * gridDim.x + blockIdx.x;
    int swz = (lin & 7) * (nwg >> 3) + (lin >> 3);
    int bx = swz % gridDim.x, by = swz / gridDim.x;
    const size_t m0 = (size_t)by * 128, n0 = (size_t)bx * 128;
    const int wm = (w >> 1) * 64, wn = (w & 1) * 64;

    f32x4 acc[4][4];
#pragma unroll
    for (int i = 0; i < 4; ++i)
#pragma unroll
        for (int j = 0; j < 4; ++j) acc[i][j] = (f32x4){0.f, 0.f, 0.f, 0.f};

    const int srow = l >> 3;
    const int schunk = (l & 7) ^ (srow & 7);
    const unsigned short* aBase = A + (m0 + srow) * (size_t)K + schunk * 8;
    const unsigned short* bBase = Bw + (n0 + srow) * (size_t)K + schunk * 8;
    const int roff = q16 & 7;

    for (int k0 = 0; k0 < K; k0 += 64) {
#pragma unroll
        for (int i = 0; i < 4; ++i) {
            size_t rstep = (size_t)(w * 4 + i) * 8 * K;
            async_ld16(&As[(w * 4 + i) * 512], aBase + rstep + k0);
            async_ld16(&Bs[(w * 4 + i) * 512], bBase + rstep + k0);
        }
        __syncthreads();
        __builtin_amdgcn_s_setprio(1);
#pragma unroll
        for (int ks = 0; ks < 2; ++ks) {
            bf16x8 af[4], bf[4];
#pragma unroll
            for (int f = 0; f < 4; ++f) {
                int off = (ks * 32 + g * 8) ^ (roff << 3);
                af[f] = *(const bf16x8*)&As[(wm + f * 16 + q16) * 64 + off];
                bf[f] = *(const bf16x8*)&Bs[(wn + f * 16 + q16) * 64 + off];
            }
#pragma unroll
            for (int fm = 0; fm < 4; ++fm)
#pragma unroll
                for (int fn = 0; fn < 4; ++fn)
                    acc[fm][fn] = __builtin_amdgcn_mfma_f32_16x16x32_bf16(
                        af[fm], bf[fn], acc[fm][fn], 0, 0, 0);
        }
        __builtin_amdgcn_s_setprio(0);
        __syncthreads();
    }

    if (Cb) {
#pragma unroll
        for (int fm = 0; fm < 4; ++fm)
#pragma unroll
            for (int r = 0; r < 4; ++r) {
                size_t base = (m0 + wm + fm * 16 + 4 * g + r) * (size_t)N + n0 + wn + q16;
#pragma unroll
                for (int fn = 0; fn < 4; ++fn)
                    Cb[base + fn * 16] = f2bf(acc[fm][fn][r]);
            }
    } else {
#pragma unroll
        for (int fm = 0; fm < 4; ++fm)
#pragma unroll
            for (int r = 0; r < 4; ++r) {
                size_t base = (m0 + wm + fm * 16 + 4 * g + r) * (size_t)N + n0 + wn + q16;
#pragma unroll
                for (int fn = 0; fn < 4; ++fn)
                    Cf[base + fn * 16] = acc[fm][fn][r];
            }
    }
}

// ---------------------------------------------------------------------------
// Pointwise prep on q,k only (in-place). (unchanged)
// ---------------------------------------------------------------------------
__global__ __launch_bounds__(256) void qkv_prep_k(
    unsigned short* __restrict__ qkv,
    const float* __restrict__ cost, const float* __restrict__ sint) {
    const int gw = (blockIdx.x * 256 + threadIdx.x) >> 6;
    const int lane = threadIdx.x & 63;
    const int h = gw & (H_ - 1);
    const int t = (gw / H_) & (T_ - 1);
    const int b = gw / (H_ * T_);
    const size_t rowbase = ((size_t)(b * T_ + t) * 3) * HDIM_ + (size_t)h * D_;
    const float c = (lane < 32) ? cost[t * 32 + lane] : 1.0f;
    const float s = (lane < 32) ? sint[t * 32 + lane] : 0.0f;
    const float EPS = 1.1920928955078125e-07f;

#pragma unroll
    for (int qk = 0; qk < 2; ++qk) {
        unsigned short* p = qkv + rowbase + (size_t)qk * HDIM_;
        float x1 = bf2f(p[lane]), x2 = bf2f(p[lane + 64]);
        float ss = x1 * x1 + x2 * x2;
#pragma unroll
        for (int m = 32; m >= 1; m >>= 1) ss += __shfl_xor(ss, m, 64);
        float r = 1.0f / sqrtf(ss * (1.0f / 128.0f) + EPS);
        x1 *= r; x2 *= r;
        p[lane]      = f2bf(x1 * c + x2 * s);
        p[lane + 64] = f2bf(x2 * c - x1 * s);
    }
}

// ---------------------------------------------------------------------------
// V blend + transpose -> vT[b][h][d][t]. (unchanged)
// ---------------------------------------------------------------------------
__global__ __launch_bounds__(256) void vtrans_k(
    const unsigned short* __restrict__ qkv, const float* __restrict__ ve,
    const float* __restrict__ lambdas, unsigned short* __restrict__ vT) {
    __shared__ unsigned short lds[64][65];
    const int tid = threadIdx.x;
    const int d0 = blockIdx.x * 64, t0 = blockIdx.y * 64;
    const int p = blockIdx.z;
    const int h = p & 7, b = p >> 3;
    const float l0 = lambdas[0], l1 = lambdas[1];

#pragma unroll
    for (int u = 0; u < 2; ++u) {
        int unit = tid + u * 256;
        int i = unit >> 3, jc = (unit & 7) * 8;
        size_t row = (size_t)(b * T_ + t0 + i);
        ushort8 vv = *(const ushort8*)&qkv[(row * 3 + 2) * HDIM_ + h * D_ + d0 + jc];
        const float* pe = &ve[row * HDIM_ + h * D_ + d0 + jc];
        float4 e0 = *(const float4*)pe;
        float4 e1 = *(const float4*)(pe + 4);
        lds[i][jc + 0] = f2bf(l0 * bf2f(vv[0]) + l1 * e0.x);
        lds[i][jc + 1] = f2bf(l0 * bf2f(vv[1]) + l1 * e0.y);
        lds[i][jc + 2] = f2bf(l0 * bf2f(vv[2]) + l1 * e0.z);
        lds[i][jc + 3] = f2bf(l0 * bf2f(vv[3]) + l1 * e0.w);
        lds[i][jc + 4] = f2bf(l0 * bf2f(vv[4]) + l1 * e1.x);
        lds[i][jc + 5] = f2bf(l0 * bf2f(vv[5]) + l1 * e1.y);
        lds[i][jc + 6] = f2bf(l0 * bf2f(vv[6]) + l1 * e1.z);
        lds[i][jc + 7] = f2bf(l0 * bf2f(vv[7]) + l1 * e1.w);
    }
    __syncthreads();
#pragma unroll
    for (int u = 0; u < 2; ++u) {
        int unit = tid + u * 256;
        int r = unit >> 3, tc = (unit & 7) * 8;
        ushort8 o;
#pragma unroll
        for (int m = 0; m < 8; ++m) o[m] = lds[tc + m][r];
        *(ushort8*)&vT[((size_t)(b * H_ + h) * D_ + d0 + r) * T_ + t0 + tc] = o;
    }
}

// ---------------------------------------------------------------------------
// MFMA flash attention. 512 thr = 8 waves; one (b,h,qtile=128); wave w owns
// q-rows [q0+16w,+16). KV tiles of 64, DOUBLE-BUFFERED: stage(next) issued
// right after the barrier, compute(cur) overlaps the loads, one barrier/iter.
// Swapped QK^T; K from qkv, V from vT, both pre-swizzled global_load_lds.
// Pt written as b64 4-short packs (conflict-free). Defer-max THR=8.
// LDS 80KB -> 2 blocks/CU. Grid 512 XCD-clustered, heavy q-tiles first.
// ---------------------------------------------------------------------------
__global__ __launch_bounds__(512, 4) void attn_mfma(
    const unsigned short* __restrict__ qkv, const unsigned short* __restrict__ vT,
    unsigned short* __restrict__ y) {
    __shared__ __align__(16) unsigned short Ks[2][64 * 128];   // 32KB
    __shared__ __align__(16) unsigned short Vs[2][128 * 64];   // 32KB
    __shared__ __align__(16) unsigned short Pt[8][16 * 64];    // 16KB

    const int tid = threadIdx.x;
    const int l = tid & 63, w = tid >> 6;       // 8 waves
    const int g = l >> 4, q16 = l & 15;
    // XCD-clustered decode: each XCD owns 4 (b,h) pairs x 16 q-tiles
    const int bid = blockIdx.x;
    const int xcd = bid & 7, slot = bid >> 3;
    const int pord = slot >> 4, qo = slot & 15;
    const int p = pord * 8 + xcd;
    const int h = p & 7, b = p >> 3;
    const int qt = 15 - qo;                     // heavy tiles first
    const int q0 = qt * 128;
    const int roff = q16 & 7;

    // staging geometry: wave w issues loads j = w*2, w*2+1 for both K and V
    const int jk0 = w * 2;
    const int krow0 = jk0 * 4 + g,        krow1 = (jk0 + 1) * 4 + g;
    const int kch0  = q16 ^ (krow0 & 7),  kch1  = q16 ^ (krow1 & 7);
    const int vrow0 = jk0 * 8 + (l >> 3), vrow1 = (jk0 + 1) * 8 + (l >> 3);
    const int vch0  = (l & 7) ^ (vrow0 & 7), vch1 = (l & 7) ^ (vrow1 & 7);
    const unsigned short* kp0 =
        &qkv[((size_t)(b * T_ + krow0) * 3 + 1) * HDIM_ + h * D_ + kch0 * 8];
    const unsigned short* kp1 =
        &qkv[((size_t)(b * T_ + krow1) * 3 + 1) * HDIM_ + h * D_ + kch1 * 8];
    const unsigned short* vp0 =
        &vT[((size_t)(b * H_ + h) * D_ + vrow0) * T_ + vch0 * 8];
    const unsigned short* vp1 =
        &vT[((size_t)(b * H_ + h) * D_ + vrow1) * T_ + vch1 * 8];
    const size_t kstep = (size_t)64 * 3 * HDIM_;   // 64 kv rows

#define STAGE_KV(buf, it_) do {                                   \
        size_t ko_ = (size_t)(it_) * kstep; int vo_ = (it_) * 64; \
        async_ld16(&Ks[buf][jk0 * 512],       kp0 + ko_);         \
        async_ld16(&Ks[buf][(jk0 + 1) * 512], kp1 + ko_);         \
        async_ld16(&Vs[buf][jk0 * 512],       vp0 + vo_);         \
        async_ld16(&Vs[buf][(jk0 + 1) * 512], vp1 + vo_);         \
    } while (0)

    // Q fragments: lane row q0+16w+q16, 8 contiguous d per kslice
    const int qrow = q0 + w * 16 + q16;
    const size_t qbase = ((size_t)(b * T_ + qrow) * 3) * HDIM_ + (size_t)h * D_;
    bf16x8 qf[4];
#pragma unroll
    for (int ks = 0; ks < 4; ++ks)
        qf[ks] = *(const bf16x8*)&qkv[qbase + ks * 32 + g * 8];

    f32x4 accO[8];
#pragma unroll
    for (int i = 0; i < 8; ++i) accO[i] = (f32x4){0.f, 0.f, 0.f, 0.f};
    float m_s = -1e30f, l_s = 0.f;

    const int nkv = 2 * qt + 2;
    int cur = 0;
    STAGE_KV(0, 0);

    for (int it = 0; it < nkv; ++it) {
        const int kv0 = it * 64;
        __syncthreads();   // drains vmcnt -> buf[cur] ready; all waves past reads of buf[cur^1]
        if (it + 1 < nkv) STAGE_KV(cur ^ 1, it + 1);

        // ---- S^T = K * Q^T (16 MFMA) ----
        f32x4 st[4];
        __builtin_amdgcn_s_setprio(1);
#pragma unroll
        for (int fk = 0; fk < 4; ++fk) {
            f32x4 a = (f32x4){0.f, 0.f, 0.f, 0.f};
            int row = fk * 16 + q16;
#pragma unroll
            for (int ks = 0; ks < 4; ++ks) {
                bf16x8 kf = *(const bf16x8*)&Ks[cur][row * 128 +
                                                ((ks * 32 + g * 8) ^ (roff << 3))];
                a = __builtin_amdgcn_mfma_f32_16x16x32_bf16(kf, qf[ks], a, 0, 0, 0);
            }
            st[fk] = a;
        }
        __builtin_amdgcn_s_setprio(0);

        // ---- online softmax over kv (per q-col = q16) ----
        float sv[4][4];
        float pmax = -1e30f;
        const bool edge = (kv0 + 64 > q0);
#pragma unroll
        for (int fk = 0; fk < 4; ++fk)
#pragma unroll
            for (int r = 0; r < 4; ++r) {
                float sc_ = st[fk][r] * ATTN_SCALE;
                if (edge) {
                    int kvg = kv0 + fk * 16 + 4 * g + r;
                    if (kvg > qrow) sc_ = -1e30f;
                }
                sv[fk][r] = sc_;
                pmax = fmaxf(pmax, sc_);
            }
        pmax = fmaxf(pmax, __shfl_xor(pmax, 16));
        pmax = fmaxf(pmax, __shfl_xor(pmax, 32));

        // defer-max: skip O-rescale while the running max doesn't grow by >8
        if (!__all(pmax - m_s <= 8.0f)) {
            float mnew = fmaxf(m_s, pmax);
            float scl = __expf(m_s - mnew);
            m_s = mnew;
            l_s *= scl;
            f32x4 scv;
            scv[0] = __shfl(scl, 4 * g + 0);
            scv[1] = __shfl(scl, 4 * g + 1);
            scv[2] = __shfl(scl, 4 * g + 2);
            scv[3] = __shfl(scl, 4 * g + 3);
#pragma unroll
            for (int fo = 0; fo < 8; ++fo) accO[fo] *= scv;
        }

        float rsum = 0.f;
#pragma unroll
        for (int fk = 0; fk < 4; ++fk)
#pragma unroll
            for (int r = 0; r < 4; ++r) {
                sv[fk][r] = __expf(sv[fk][r] - m_s);
                rsum += sv[fk][r];
            }
        rsum += __shfl_xor(rsum, 16);
        rsum += __shfl_xor(rsum, 32);
        l_s += rsum;

        // ---- pack P -> per-wave LDS (bf16, swizzled, b64 = conflict-free) ----
#pragma unroll
        for (int fk = 0; fk < 4; ++fk) {
            unsigned long long pk =
                (unsigned long long)f2bf(sv[fk][0])        |
                ((unsigned long long)f2bf(sv[fk][1]) << 16) |
                ((unsigned long long)f2bf(sv[fk][2]) << 32) |
                ((unsigned long long)f2bf(sv[fk][3]) << 48);
            int kv = fk * 16 + 4 * g;
            *(unsigned long long*)&Pt[w][q16 * 64 + (kv ^ (roff << 3))] = pk;
        }

        // ---- PV: O += P * V (16 MFMA) ----
        bf16x8 pa[2];
#pragma unroll
        for (int ks = 0; ks < 2; ++ks)
            pa[ks] = *(const bf16x8*)&Pt[w][q16 * 64 + ((ks * 32 + g * 8) ^ (roff << 3))];
        __builtin_amdgcn_s_setprio(1);
#pragma unroll
        for (int fo = 0; fo < 8; ++fo) {
            int drow = fo * 16 + q16;
#pragma unroll
            for (int ks = 0; ks < 2; ++ks) {
                bf16x8 vf = *(const bf16x8*)&Vs[cur][drow * 64 +
                                                ((ks * 32 + g * 8) ^ (roff << 3))];
                accO[fo] = __builtin_amdgcn_mfma_f32_16x16x32_bf16(pa[ks], vf, accO[fo], 0, 0, 0);
            }
        }
        __builtin_amdgcn_s_setprio(0);
        cur ^= 1;
    }
#undef STAGE_KV

    // ---- epilogue: y[b, t, h*128 + d] = O / l ----
    float inv = 1.0f / l_s;
    f32x4 iv;
    iv[0] = __shfl(inv, 4 * g + 0);
    iv[1] = __shfl(inv, 4 * g + 1);
    iv[2] = __shfl(inv, 4 * g + 2);
    iv[3] = __shfl(inv, 4 * g + 3);
#pragma unroll
    for (int r = 0; r < 4; ++r) {
        size_t yb = ((size_t)(b * T_ + q0 + w * 16 + 4 * g + r)) * HDIM_ +
                    (size_t)h * D_ + q16;
#pragma unroll
        for (int fo = 0; fo < 8; ++fo)
            y[yb + fo * 16] = f2bf(accO[fo][r] * iv[r]);
    }
}

// ---------------------------------------------------------------------------
// Workspace (bytes):
//   qkv bf16 [0,48M)  y [48M,64M)  xb [64M,80M)  wb [80M,86M)  pb [86M,88M)
//   cos/sin f32 [88M,88.5M)  vT bf16 [96M,112M)
// ---------------------------------------------------------------------------
extern "C" void kernel_launch(void* const* d_in, const int* in_sizes, int n_in,
                              void* d_out, int out_size, void* d_ws, size_t ws_size,
                              hipStream_t stream) {
    (void)in_sizes; (void)n_in; (void)out_size; (void)ws_size;
    const float* x        = (const float*)d_in[0];
    const float* ve       = (const float*)d_in[1];
    const float* qkv_w    = (const float*)d_in[2];
    const float* lambdas  = (const float*)d_in[3];
    const float* c_proj_w = (const float*)d_in[4];
    float* out = (float*)d_out;

    char* ws = (char*)d_ws;
    unsigned short* qkv = (unsigned short*)ws;                             // 8192*3072
    unsigned short* y   = (unsigned short*)(ws + 50331648);                // 8192*1024
    unsigned short* xb  = (unsigned short*)(ws + 67108864);                // 8192*1024
    unsigned short* wb  = (unsigned short*)(ws + 83886080);                // 3072*1024
    unsigned short* pb  = (unsigned short*)(ws + 90177536);                // 1024*1024
    float* cost = (float*)(ws + 92274688);                                 // 2048*32
    float* sint = cost + T_ * 32;
    unsigned short* vT  = (unsigned short*)(ws + 100663296);               // 32*128*2048

    hipLaunchKernelGGL(cvtk, dim3(8192), dim3(256), 0, stream, x, xb, 8192 * 1024 / 4);
    hipLaunchKernelGGL(cvtk, dim3(3072), dim3(256), 0, stream, qkv_w, wb, 3072 * 1024 / 4);
    hipLaunchKernelGGL(cvtk, dim3(1024), dim3(256), 0, stream, c_proj_w, pb, 1024 * 1024 / 4);
    hipLaunchKernelGGL(rope_tables_k, dim3(256), dim3(256), 0, stream, cost, sint);

    hipLaunchKernelGGL(gemm_bf16_nt, dim3(24, 64), dim3(256), 0, stream,
                       xb, wb, (float*)nullptr, qkv, B_ * T_, 3 * HDIM_, DIM_);
    hipLaunchKernelGGL(qkv_prep_k, dim3(B_ * T_ * H_ / 4), dim3(256), 0, stream,
                       qkv, cost, sint);
    hipLaunchKernelGGL(vtrans_k, dim3(2, 32, 32), dim3(256), 0, stream,
                       qkv, ve, lambdas, vT);
    hipLaunchKernelGGL(attn_mfma, dim3(512), dim3(512), 0, stream, qkv, vT, y);
    hipLaunchKernelGGL(gemm_bf16_nt, dim3(8, 64), dim3(256), 0, stream,
                       y, pb, out, (unsigned short*)nullptr, B_ * T_, DIM_, HDIM_);
}

// Round 6
// 332.083 us; speedup vs baseline: 1.0245x; 1.0245x over previous
//
#include <hip/hip_runtime.h>
#include <hip/hip_bf16.h>

constexpr int B_ = 4;
constexpr int T_ = 2048;
constexpr int DIM_ = 1024;
constexpr int H_ = 8;
constexpr int D_ = 128;
constexpr int HDIM_ = H_ * D_;   // 1024

typedef __attribute__((ext_vector_type(8))) short bf16x8;
typedef __attribute__((ext_vector_type(8))) unsigned short ushort8;
typedef __attribute__((ext_vector_type(4))) float f32x4;
typedef __attribute__((ext_vector_type(16))) float f32x16;

#define ATTN_SCALE 0.08838834764831845f

__device__ __forceinline__ unsigned short f2bf(float x) {
    unsigned u = __float_as_uint(x);
    unsigned r = (u + 0x7FFFu + ((u >> 16) & 1u)) >> 16;
    return (unsigned short)r;
}
__device__ __forceinline__ float bf2f(unsigned short u) {
    return __uint_as_float(((unsigned)u) << 16);
}

// async 16B global -> LDS (dest: wave-uniform base + lane*16; src: per-lane)
__device__ __forceinline__ void async_ld16(void* ldsdst, const void* gsrc) {
    __builtin_amdgcn_global_load_lds(
        (const __attribute__((address_space(1))) unsigned int*)gsrc,
        (__attribute__((address_space(3))) unsigned int*)ldsdst, 16, 0, 0);
}

// ---------------------------------------------------------------------------
// f32 -> bf16 convert, 4 elems/thread
// ---------------------------------------------------------------------------
__global__ __launch_bounds__(256) void cvtk(const float* __restrict__ in,
                                            unsigned short* __restrict__ out, int n4) {
    int i = blockIdx.x * 256 + threadIdx.x;
    if (i < n4) {
        float4 v = ((const float4*)in)[i];
        ushort4 o;
        o.x = f2bf(v.x); o.y = f2bf(v.y); o.z = f2bf(v.z); o.w = f2bf(v.w);
        ((ushort4*)out)[i] = o;
    }
}

// ---------------------------------------------------------------------------
// RoPE tables (f32): cos/sin[t][j], j<32 real freqs; j>=32 identity.
// ---------------------------------------------------------------------------
__global__ void rope_tables_k(float* __restrict__ cost, float* __restrict__ sint) {
    int idx = blockIdx.x * blockDim.x + threadIdx.x;
    if (idx >= T_ * 32) return;
    int t = idx >> 5, j = idx & 31;
    float e = (float)j * (1.0f / 31.0f);
    float freq = powf(1.0f / 1024.0f, e);
    float th = (float)t * freq;
    cost[idx] = cosf(th);
    sint[idx] = sinf(th);
}

// ---------------------------------------------------------------------------
// bf16 NT GEMM: C[M,N] = A[M,K] * B[N,K]^T, 128x128 tile, BK=64, 4 waves 2x2.
// (unchanged — verified)
// ---------------------------------------------------------------------------
__global__ __launch_bounds__(256) void gemm_bf16_nt(
    const unsigned short* __restrict__ A, const unsigned short* __restrict__ Bw,
    float* __restrict__ Cf, unsigned short* __restrict__ Cb,
    int M, int N, int K) {
    __shared__ __align__(16) unsigned short As[128 * 64];
    __shared__ __align__(16) unsigned short Bs[128 * 64];
    const int tid = threadIdx.x;
    const int l = tid & 63, w = tid >> 6;
    const int g = l >> 4, q16 = l & 15;

    int nwg = gridDim.x * gridDim.y;
    int lin = blockIdx.y * gridDim.x + blockIdx.x;
    int swz = (lin & 7) * (nwg >> 3) + (lin >> 3);
    int bx = swz % gridDim.x, by = swz / gridDim.x;
    const size_t m0 = (size_t)by * 128, n0 = (size_t)bx * 128;
    const int wm = (w >> 1) * 64, wn = (w & 1) * 64;

    f32x4 acc[4][4];
#pragma unroll
    for (int i = 0; i < 4; ++i)
#pragma unroll
        for (int j = 0; j < 4; ++j) acc[i][j] = (f32x4){0.f, 0.f, 0.f, 0.f};

    const int srow = l >> 3;
    const int schunk = (l & 7) ^ (srow & 7);
    const unsigned short* aBase = A + (m0 + srow) * (size_t)K + schunk * 8;
    const unsigned short* bBase = Bw + (n0 + srow) * (size_t)K + schunk * 8;
    const int roff = q16 & 7;

    for (int k0 = 0; k0 < K; k0 += 64) {
#pragma unroll
        for (int i = 0; i < 4; ++i) {
            size_t rstep = (size_t)(w * 4 + i) * 8 * K;
            async_ld16(&As[(w * 4 + i) * 512], aBase + rstep + k0);
            async_ld16(&Bs[(w * 4 + i) * 512], bBase + rstep + k0);
        }
        __syncthreads();
        __builtin_amdgcn_s_setprio(1);
#pragma unroll
        for (int ks = 0; ks < 2; ++ks) {
            bf16x8 af[4], bf[4];
#pragma unroll
            for (int f = 0; f < 4; ++f) {
                int off = (ks * 32 + g * 8) ^ (roff << 3);
                af[f] = *(const bf16x8*)&As[(wm + f * 16 + q16) * 64 + off];
                bf[f] = *(const bf16x8*)&Bs[(wn + f * 16 + q16) * 64 + off];
            }
#pragma unroll
            for (int fm = 0; fm < 4; ++fm)
#pragma unroll
                for (int fn = 0; fn < 4; ++fn)
                    acc[fm][fn] = __builtin_amdgcn_mfma_f32_16x16x32_bf16(
                        af[fm], bf[fn], acc[fm][fn], 0, 0, 0);
        }
        __builtin_amdgcn_s_setprio(0);
        __syncthreads();
    }

    if (Cb) {
#pragma unroll
        for (int fm = 0; fm < 4; ++fm)
#pragma unroll
            for (int r = 0; r < 4; ++r) {
                size_t base = (m0 + wm + fm * 16 + 4 * g + r) * (size_t)N + n0 + wn + q16;
#pragma unroll
                for (int fn = 0; fn < 4; ++fn)
                    Cb[base + fn * 16] = f2bf(acc[fm][fn][r]);
            }
    } else {
#pragma unroll
        for (int fm = 0; fm < 4; ++fm)
#pragma unroll
            for (int r = 0; r < 4; ++r) {
                size_t base = (m0 + wm + fm * 16 + 4 * g + r) * (size_t)N + n0 + wn + q16;
#pragma unroll
                for (int fn = 0; fn < 4; ++fn)
                    Cf[base + fn * 16] = acc[fm][fn][r];
            }
    }
}

// ---------------------------------------------------------------------------
// Pointwise prep on q,k only (in-place). (unchanged)
// ---------------------------------------------------------------------------
__global__ __launch_bounds__(256) void qkv_prep_k(
    unsigned short* __restrict__ qkv,
    const float* __restrict__ cost, const float* __restrict__ sint) {
    const int gw = (blockIdx.x * 256 + threadIdx.x) >> 6;
    const int lane = threadIdx.x & 63;
    const int h = gw & (H_ - 1);
    const int t = (gw / H_) & (T_ - 1);
    const int b = gw / (H_ * T_);
    const size_t rowbase = ((size_t)(b * T_ + t) * 3) * HDIM_ + (size_t)h * D_;
    const float c = (lane < 32) ? cost[t * 32 + lane] : 1.0f;
    const float s = (lane < 32) ? sint[t * 32 + lane] : 0.0f;
    const float EPS = 1.1920928955078125e-07f;

#pragma unroll
    for (int qk = 0; qk < 2; ++qk) {
        unsigned short* p = qkv + rowbase + (size_t)qk * HDIM_;
        float x1 = bf2f(p[lane]), x2 = bf2f(p[lane + 64]);
        float ss = x1 * x1 + x2 * x2;
#pragma unroll
        for (int m = 32; m >= 1; m >>= 1) ss += __shfl_xor(ss, m, 64);
        float r = 1.0f / sqrtf(ss * (1.0f / 128.0f) + EPS);
        x1 *= r; x2 *= r;
        p[lane]      = f2bf(x1 * c + x2 * s);
        p[lane + 64] = f2bf(x2 * c - x1 * s);
    }
}

// ---------------------------------------------------------------------------
// V blend + transpose -> vT[b][h][d][t]. (unchanged)
// ---------------------------------------------------------------------------
__global__ __launch_bounds__(256) void vtrans_k(
    const unsigned short* __restrict__ qkv, const float* __restrict__ ve,
    const float* __restrict__ lambdas, unsigned short* __restrict__ vT) {
    __shared__ unsigned short lds[64][65];
    const int tid = threadIdx.x;
    const int d0 = blockIdx.x * 64, t0 = blockIdx.y * 64;
    const int p = blockIdx.z;
    const int h = p & 7, b = p >> 3;
    const float l0 = lambdas[0], l1 = lambdas[1];

#pragma unroll
    for (int u = 0; u < 2; ++u) {
        int unit = tid + u * 256;
        int i = unit >> 3, jc = (unit & 7) * 8;
        size_t row = (size_t)(b * T_ + t0 + i);
        ushort8 vv = *(const ushort8*)&qkv[(row * 3 + 2) * HDIM_ + h * D_ + d0 + jc];
        const float* pe = &ve[row * HDIM_ + h * D_ + d0 + jc];
        float4 e0 = *(const float4*)pe;
        float4 e1 = *(const float4*)(pe + 4);
        lds[i][jc + 0] = f2bf(l0 * bf2f(vv[0]) + l1 * e0.x);
        lds[i][jc + 1] = f2bf(l0 * bf2f(vv[1]) + l1 * e0.y);
        lds[i][jc + 2] = f2bf(l0 * bf2f(vv[2]) + l1 * e0.z);
        lds[i][jc + 3] = f2bf(l0 * bf2f(vv[3]) + l1 * e0.w);
        lds[i][jc + 4] = f2bf(l0 * bf2f(vv[4]) + l1 * e1.x);
        lds[i][jc + 5] = f2bf(l0 * bf2f(vv[5]) + l1 * e1.y);
        lds[i][jc + 6] = f2bf(l0 * bf2f(vv[6]) + l1 * e1.z);
        lds[i][jc + 7] = f2bf(l0 * bf2f(vv[7]) + l1 * e1.w);
    }
    __syncthreads();
#pragma unroll
    for (int u = 0; u < 2; ++u) {
        int unit = tid + u * 256;
        int r = unit >> 3, tc = (unit & 7) * 8;
        ushort8 o;
#pragma unroll
        for (int m = 0; m < 8; ++m) o[m] = lds[tc + m][r];
        *(ushort8*)&vT[((size_t)(b * H_ + h) * D_ + d0 + r) * T_ + t0 + tc] = o;
    }
}

// ---------------------------------------------------------------------------
// MFMA flash attention, 32x32x16 MFMA. 256 thr = 4 waves; block owns one
// (b,h,qtile=128); wave owns 32 q-cols. KV tiles of 64, double-buffered.
// Swapped QK^T: S^T = mfma(A=K[kv rows], B=Q[q cols]) -> lane holds q-col
// l&31, 16 kv rows/m-tile in C regs. Softmax fully in-lane + 1 shfl_xor(32).
// P stays in REGISTERS: repacked to the PV B-operand layout via 8
// shfl_xor(32) per m-tile (no P LDS round-trip). PV: O^T = mfma(A=V^T, B=P).
// LDS 64KB -> 2 blocks/CU. Balanced decode: co-resident pair (bid, bid+256)
// has qt and 15-qt (const 36 kv-iters per CU).
// ---------------------------------------------------------------------------
__global__ __launch_bounds__(256, 2) void attn_mfma(
    const unsigned short* __restrict__ qkv, const unsigned short* __restrict__ vT,
    unsigned short* __restrict__ y) {
    __shared__ __align__(16) unsigned short Ks[2][64 * 128];   // [kv][d]
    __shared__ __align__(16) unsigned short Vs[2][128 * 64];   // [d][kv]

    const int tid = threadIdx.x;
    const int l = tid & 63, w = tid >> 6;       // 4 waves
    const int l31 = l & 31, hi = l >> 5, l7 = l & 7;
    const int bid = blockIdx.x;
    const int xcd = bid & 7, slot = bid >> 3;
    const int pord = slot >> 4, qo = slot & 15;
    const int p = pord * 8 + xcd;               // 4 (b,h) pairs per XCD (L2-fit)
    const int h = p & 7, b = p >> 3;
    const int qt = (pord < 2) ? (15 - qo) : qo; // pair-sum = 15 => balanced CUs
    const int q0 = qt * 128;

    // ---- staging pointers: wave w owns units w*4+i (K: 4 kv rows; V: 8 d rows)
    const unsigned short* kp[4];
    const unsigned short* vp[4];
#pragma unroll
    for (int i = 0; i < 4; ++i) {
        int r = 16 * w + 4 * i + (l >> 4);      // kv row in tile
        int kch = (l & 15) ^ (r & 7);
        kp[i] = &qkv[((size_t)(b * T_ + r) * 3 + 1) * HDIM_ + h * D_ + kch * 8];
        int d = 32 * w + 8 * i + (l >> 3);      // d row
        int vch = l7 ^ (d & 7);
        vp[i] = &vT[((size_t)(b * H_ + h) * D_ + d) * T_ + vch * 8];
    }
#define STAGE_KV(buf, it_) do {                                        \
        size_t ko_ = (size_t)(it_) * (64 * 3 * HDIM_);                 \
        int vo_ = (it_) * 64;                                          \
        _Pragma("unroll")                                              \
        for (int i_ = 0; i_ < 4; ++i_) {                               \
            async_ld16(&Ks[buf][(w * 4 + i_) * 512], kp[i_] + ko_);    \
            async_ld16(&Vs[buf][(w * 4 + i_) * 512], vp[i_] + vo_);    \
        }                                                              \
    } while (0)

    // ---- Q fragments (B-operand): lane q-col qc, k = d = ks*16 + hi*8 + j
    const int qc = q0 + w * 32 + l31;
    const size_t qbase = ((size_t)(b * T_ + qc) * 3) * HDIM_ + (size_t)h * D_;
    bf16x8 qf[8];
#pragma unroll
    for (int ks = 0; ks < 8; ++ks)
        qf[ks] = *(const bf16x8*)&qkv[qbase + ks * 16 + hi * 8];

    f32x16 accO[4];
#pragma unroll
    for (int i = 0; i < 4; ++i) accO[i] = (f32x16)(0.f);
    float m_s = -1e30f, l_s = 0.f;

    const int nkv = 2 * qt + 2;
    int cur = 0;
    STAGE_KV(0, 0);

    for (int it = 0; it < nkv; ++it) {
        const int kv0 = it * 64;
        __syncthreads();   // buf[cur] staged; all waves done with buf[cur^1]
        if (it + 1 < nkv) STAGE_KV(cur ^ 1, it + 1);

        // ---- S^T = K * Q^T (2 m-tiles x 8 k-slices of 32x32x16) ----
        f32x16 st[2];
        __builtin_amdgcn_s_setprio(1);
#pragma unroll
        for (int mt = 0; mt < 2; ++mt) {
            f32x16 a = (f32x16)(0.f);
            int row = mt * 32 + l31;
#pragma unroll
            for (int ks = 0; ks < 8; ++ks) {
                bf16x8 kf = *(const bf16x8*)&Ks[cur][row * 128 +
                                                     8 * ((2 * ks + hi) ^ l7)];
                a = __builtin_amdgcn_mfma_f32_32x32x16_bf16(kf, qf[ks], a, 0, 0, 0);
            }
            st[mt] = a;
        }
        __builtin_amdgcn_s_setprio(0);

        // ---- mask + scale + row max (lane owns q-col; kv split lane<->lane+32)
        float sv[2][16];
        float pmax = -1e30f;
        const bool edge = (kv0 + 64 > q0);
#pragma unroll
        for (int mt = 0; mt < 2; ++mt)
#pragma unroll
            for (int r = 0; r < 16; ++r) {
                float x = st[mt][r] * ATTN_SCALE;
                if (edge) {
                    int kvg = kv0 + 32 * mt + (r & 3) + 8 * (r >> 2) + 4 * hi;
                    if (kvg > qc) x = -1e30f;
                }
                sv[mt][r] = x;
                pmax = fmaxf(pmax, x);
            }
        pmax = fmaxf(pmax, __shfl_xor(pmax, 32));

        // defer-max: rescale only when the running max grows by > 8
        if (!__all(pmax - m_s <= 8.0f)) {
            float mnew = fmaxf(m_s, pmax);
            float scl = __expf(m_s - mnew);
            m_s = mnew;
            l_s *= scl;
#pragma unroll
            for (int dt = 0; dt < 4; ++dt) accO[dt] *= scl;
        }

        float rsum = 0.f;
#pragma unroll
        for (int mt = 0; mt < 2; ++mt)
#pragma unroll
            for (int r = 0; r < 16; ++r) {
                sv[mt][r] = __expf(sv[mt][r] - m_s);
                rsum += sv[mt][r];
            }
        rsum += __shfl_xor(rsum, 32);
        l_s += rsum;

        // ---- repack P (f32 C-regs) -> PV B-frags (bf16), in-register ----
        // own kv (per mt) = 8s + 4hi + t; partner half via shfl_xor(32).
        bf16x8 pb[4];
#pragma unroll
        for (int mt = 0; mt < 2; ++mt) {
            unsigned w0[4], w1[4], sw0[4], sw1[4];
#pragma unroll
            for (int s = 0; s < 4; ++s) {
                w0[s] = (unsigned)f2bf(sv[mt][4 * s + 0]) |
                        ((unsigned)f2bf(sv[mt][4 * s + 1]) << 16);
                w1[s] = (unsigned)f2bf(sv[mt][4 * s + 2]) |
                        ((unsigned)f2bf(sv[mt][4 * s + 3]) << 16);
            }
#pragma unroll
            for (int s = 0; s < 4; ++s) {
                sw0[s] = __shfl_xor(w0[s], 32);
                sw1[s] = __shfl_xor(w1[s], 32);
            }
#pragma unroll
            for (int ktl = 0; ktl < 2; ++ktl) {
                union { unsigned u[4]; bf16x8 v; } pu;
                pu.u[0] = hi ? sw0[2 * ktl + 1] : w0[2 * ktl];
                pu.u[1] = hi ? sw1[2 * ktl + 1] : w1[2 * ktl];
                pu.u[2] = hi ? w0[2 * ktl + 1] : sw0[2 * ktl];
                pu.u[3] = hi ? w1[2 * ktl + 1] : sw1[2 * ktl];
                pb[mt * 2 + ktl] = pu.v;
            }
        }

        // ---- PV: O^T += V^T * P (4 d-tiles x 4 kv-slices of 32x32x16) ----
        __builtin_amdgcn_s_setprio(1);
#pragma unroll
        for (int dt = 0; dt < 4; ++dt) {
            int drow = dt * 32 + l31;
#pragma unroll
            for (int kt = 0; kt < 4; ++kt) {
                bf16x8 vf = *(const bf16x8*)&Vs[cur][drow * 64 +
                                                     8 * ((2 * kt + hi) ^ l7)];
                accO[dt] = __builtin_amdgcn_mfma_f32_32x32x16_bf16(vf, pb[kt],
                                                                   accO[dt], 0, 0, 0);
            }
        }
        __builtin_amdgcn_s_setprio(0);
        cur ^= 1;
    }
#undef STAGE_KV

    // ---- epilogue: y[b, qc, h*128 + d] = O / l; 4 consecutive d per store ----
    float inv = 1.0f / l_s;
    const size_t yb = (size_t)(b * T_ + qc) * HDIM_ + (size_t)h * D_;
#pragma unroll
    for (int dt = 0; dt < 4; ++dt)
#pragma unroll
        for (int s = 0; s < 4; ++s) {
            ushort4 o;
            o.x = f2bf(accO[dt][4 * s + 0] * inv);
            o.y = f2bf(accO[dt][4 * s + 1] * inv);
            o.z = f2bf(accO[dt][4 * s + 2] * inv);
            o.w = f2bf(accO[dt][4 * s + 3] * inv);
            *(ushort4*)&y[yb + dt * 32 + 8 * s + 4 * hi] = o;
        }
}

// ---------------------------------------------------------------------------
// Workspace (bytes):
//   qkv bf16 [0,48M)  y [48M,64M)  xb [64M,80M)  wb [80M,86M)  pb [86M,88M)
//   cos/sin f32 [88M,88.5M)  vT bf16 [96M,112M)
// ---------------------------------------------------------------------------
extern "C" void kernel_launch(void* const* d_in, const int* in_sizes, int n_in,
                              void* d_out, int out_size, void* d_ws, size_t ws_size,
                              hipStream_t stream) {
    (void)in_sizes; (void)n_in; (void)out_size; (void)ws_size;
    const float* x        = (const float*)d_in[0];
    const float* ve       = (const float*)d_in[1];
    const float* qkv_w    = (const float*)d_in[2];
    const float* lambdas  = (const float*)d_in[3];
    const float* c_proj_w = (const float*)d_in[4];
    float* out = (float*)d_out;

    char* ws = (char*)d_ws;
    unsigned short* qkv = (unsigned short*)ws;                             // 8192*3072
    unsigned short* y   = (unsigned short*)(ws + 50331648);                // 8192*1024
    unsigned short* xb  = (unsigned short*)(ws + 67108864);                // 8192*1024
    unsigned short* wb  = (unsigned short*)(ws + 83886080);                // 3072*1024
    unsigned short* pb  = (unsigned short*)(ws + 90177536);                // 1024*1024
    float* cost = (float*)(ws + 92274688);                                 // 2048*32
    float* sint = cost + T_ * 32;
    unsigned short* vT  = (unsigned short*)(ws + 100663296);               // 32*128*2048

    hipLaunchKernelGGL(cvtk, dim3(8192), dim3(256), 0, stream, x, xb, 8192 * 1024 / 4);
    hipLaunchKernelGGL(cvtk, dim3(3072), dim3(256), 0, stream, qkv_w, wb, 3072 * 1024 / 4);
    hipLaunchKernelGGL(cvtk, dim3(1024), dim3(256), 0, stream, c_proj_w, pb, 1024 * 1024 / 4);
    hipLaunchKernelGGL(rope_tables_k, dim3(256), dim3(256), 0, stream, cost, sint);

    hipLaunchKernelGGL(gemm_bf16_nt, dim3(24, 64), dim3(256), 0, stream,
                       xb, wb, (float*)nullptr, qkv, B_ * T_, 3 * HDIM_, DIM_);
    hipLaunchKernelGGL(qkv_prep_k, dim3(B_ * T_ * H_ / 4), dim3(256), 0, stream,
                       qkv, cost, sint);
    hipLaunchKernelGGL(vtrans_k, dim3(2, 32, 32), dim3(256), 0, stream,
                       qkv, ve, lambdas, vT);
    hipLaunchKernelGGL(attn_mfma, dim3(512), dim3(256), 0, stream, qkv, vT, y);
    hipLaunchKernelGGL(gemm_bf16_nt, dim3(8, 64), dim3(256), 0, stream,
                       y, pb, out, (unsigned short*)nullptr, B_ * T_, DIM_, HDIM_);
}